// Round 6
// baseline (329.284 us; speedup 1.0000x reference)
//
#include <hip/hip_runtime.h>
#include <hip/hip_cooperative_groups.h>

// Chamfer forward: dist0[i] = min_j ||pc0[i]-pc1[j]||^2 ; out = mean(dist0[dist0<=2])
// N = M = 65536 i.i.d. N(0,1)^3 points, fp32.
// R5 (resubmitted after GPU-acquisition timeout): cooperative mega-kernel,
// GRID=256 x BLOCK=1024 (1 block/CU, most conservative co-residency) after
// R4's GRID=1024x256 exact-fit cooperative launch was REJECTED (out stayed 0;
// absmax error == reference absmax exactly). Same algorithm as R4/R3:
// zero -> count -> unified scan over 2*NC -> scatter -> query (4 sublanes)
// -> pending (branch-and-bound prune) -> reduce.
// INSURANCE: if hipLaunchCooperativeKernel returns an error at enqueue time,
// fall back to the R3 multi-kernel pipeline (verified 139.1us) on the same
// stream; slab layout is shared (counts1|counts0 = countsAll, cur1|cur0 =
// curAll, s|q = sAll).

namespace cg = cooperative_groups;

constexpr int   NPTS  = 65536;
constexpr int   G     = 64;
constexpr int   NC    = G * G * G;    // 262144 fine cells
constexpr float H     = 0.125f;
constexpr float ORG   = -4.0f;
constexpr float INVH  = 8.0f;
constexpr int   G3    = 32;           // medium geometry (phase-2 rings)
constexpr float H3    = 0.25f;
constexpr float INVH3 = 4.0f;

// mega-kernel geometry
constexpr int   BLOCK_M = 1024;       // 16 waves/block
constexpr int   GRID_M  = 256;        // 1 block/CU
constexpr int   NW_M    = GRID_M * (BLOCK_M / 64);   // 4096 waves

// fallback (R3) geometry
constexpr int   BLOCK = 256;
constexpr int   PBLOCKS = 1024;
constexpr int   SB    = 128;
constexpr int   CHUNK = NC / SB;      // 2048

__device__ __forceinline__ int cellOf(float x) {
  int c = (int)floorf((x - ORG) * INVH);
  return min(max(c, 0), G - 1);
}
__device__ __forceinline__ int cellOf3(float x) {
  int c = (int)floorf((x - ORG) * INVH3);
  return min(max(c, 0), G3 - 1);
}

// ======================= cooperative mega-kernel ==========================
__global__ __launch_bounds__(BLOCK_M, 4) void mega_kernel(
    const float* __restrict__ pc0, const float* __restrict__ pc1,
    unsigned* __restrict__ countsAll,   // [2*NC]  cells of s | cells of q
    unsigned* __restrict__ curAll,      // [2*NC]  scan -> starts -> incl. ends
    unsigned* __restrict__ partials,    // [256]
    float4*  __restrict__ sAll,         // [2*NPTS] s points | q points
    unsigned* __restrict__ wl, float* __restrict__ wlBest,
    unsigned* __restrict__ pendCnt, float* __restrict__ bkt,
    float* __restrict__ out)
{
  cg::grid_group grid = cg::this_grid();
  const int tid  = threadIdx.x;
  const int bid  = blockIdx.x;
  const int gid  = bid * BLOCK_M + tid;    // 0..262143
  const int lane = tid & 63, wid = tid >> 6;   // wid 0..15

  __shared__ unsigned shu[16];
  __shared__ float    shf[32];

  // ---- Phase 0: zero counts + misc (workspace poisoned every iter) ----
  countsAll[2 * gid]     = 0u;
  countsAll[2 * gid + 1] = 0u;
  if (bid == 0) {
    if (tid < 128) bkt[tid] = 0.f;
    else if (tid == 128) pendCnt[0] = 0u;
  }
  grid.sync();

  // ---- Phase 1: count ----
  if (gid < 2 * NPTS) {
    const float* p; unsigned* cnt; int i;
    if (gid < NPTS) { p = pc1; cnt = countsAll;      i = gid; }
    else            { p = pc0; cnt = countsAll + NC; i = gid - NPTS; }
    const float x = p[3 * i], y = p[3 * i + 1], z = p[3 * i + 2];
    atomicAdd(&cnt[(cellOf(z) * G + cellOf(y)) * G + cellOf(x)], 1u);
  }
  grid.sync();

  // ---- Phase 2a: per-block partial sums (2048 counts per block) ----
  {
    const int base = bid * 2048 + tid * 2;
    unsigned sum = countsAll[base] + countsAll[base + 1];
    for (int o = 32; o; o >>= 1) sum += __shfl_down(sum, o, 64);
    if (lane == 0) shu[wid] = sum;
    __syncthreads();
    if (tid == 0) {
      unsigned t = 0;
      for (int w = 0; w < 16; ++w) t += shu[w];
      partials[bid] = t;
    }
  }
  grid.sync();

  // ---- Phase 2b: block 0 exclusive-scans the 256 block partials ----
  if (bid == 0) {
    const unsigned vv = (tid < 256) ? partials[tid] : 0u;
    unsigned inc = vv;
    for (int o = 1; o < 64; o <<= 1) {
      const unsigned t = __shfl_up(inc, o, 64);
      if (lane >= o) inc += t;
    }
    if (lane == 63 && wid < 4) shu[wid] = inc;
    __syncthreads();
    if (tid < 256) {
      unsigned woff = 0;
      for (int w = 0; w < wid; ++w) woff += shu[w];
      partials[tid] = woff + inc - vv;
    }
  }
  grid.sync();

  // ---- Phase 2c: per-block exclusive scan + offset -> curAll starts ----
  {
    const int base = bid * 2048 + tid * 2;
    const unsigned a = countsAll[base], b2 = countsAll[base + 1];
    const unsigned ts = a + b2;
    unsigned inc = ts;
    for (int o = 1; o < 64; o <<= 1) {
      const unsigned t = __shfl_up(inc, o, 64);
      if (lane >= o) inc += t;
    }
    if (lane == 63) shu[wid] = inc;
    __syncthreads();
    unsigned woff = 0;
    for (int w = 0; w < wid; ++w) woff += shu[w];
    const unsigned off = partials[bid] + woff + inc - ts;
    curAll[base]     = off;
    curAll[base + 1] = off + a;
  }
  grid.sync();

  // ---- Phase 3: scatter (q region lands at +NPTS automatically) ----
  if (gid < 2 * NPTS) {
    const float* p; unsigned* cur; int i;
    if (gid < NPTS) { p = pc1; cur = curAll;      i = gid; }
    else            { p = pc0; cur = curAll + NC; i = gid - NPTS; }
    const float x = p[3 * i], y = p[3 * i + 1], z = p[3 * i + 2];
    const int cid = (cellOf(z) * G + cellOf(y)) * G + cellOf(x);
    sAll[atomicAdd(&cur[cid], 1u)] = make_float4(x, y, z, 0.f);
  }
  grid.sync();

  // After scatter, curAll[c] = CSR inclusive end of cell c (s part 0..NC).
  float accV = 0.f, accC = 0.f;

  // ---- Phase 4: query — fine rings 0..1, 4 sublanes per query ----
  {
    const unsigned* __restrict__ ends = curAll;
    const int i   = gid >> 2;
    const int sub = gid & 3;
    const float4 p = sAll[NPTS + i];
    const int cx = cellOf(p.x), cy = cellOf(p.y), cz = cellOf(p.z);
    const int x0 = max(cx - 1, 0), x1 = min(cx + 1, G - 1);

    unsigned rs[9], re[9];
#pragma unroll
    for (int rr = 0; rr < 9; ++rr) {
      const int zz = cz + rr / 3 - 1, yy = cy + rr % 3 - 1;
      const bool ok = (zz >= 0) && (zz < G) && (yy >= 0) && (yy < G);
      const int rb = ok ? (zz * G + yy) * G : 0;
      rs[rr] = ok ? ((rb + x0) ? ends[rb + x0 - 1] : 0u) : 0u;
      re[rr] = ok ? ends[rb + x1] : 0u;
    }
    float best = 3.4e38f;
#pragma unroll
    for (int rr = 0; rr < 9; ++rr) {
#pragma unroll 4
      for (unsigned j = rs[rr] + sub; j < re[rr]; j += 4) {
        const float4 cq = sAll[j];
        const float dx = p.x - cq.x, dy = p.y - cq.y, dz = p.z - cq.z;
        best = fminf(best, fmaf(dx, dx, fmaf(dy, dy, dz * dz)));
      }
    }
    best = fminf(best, __shfl_xor(best, 1, 64));
    best = fminf(best, __shfl_xor(best, 2, 64));

    if (sub == 0) {
      if (best > H * H) {             // not provably exact -> phase 5
        const unsigned k = atomicAdd(pendCnt, 1u);
        wl[k] = (unsigned)i; wlBest[k] = best;
      } else if (best <= 2.0f) { accV = best; accC = 1.0f; }
    }
  }
  grid.sync();

  // ---- Phase 5: pending — wave per item, medium rings over fine CSR,
  //      branch-and-bound row prune ----
  {
    const unsigned* __restrict__ ends = curAll;
    const int snP = (int)pendCnt[0];
    const int gw  = bid * (BLOCK_M / 64) + wid;

    for (int it = gw; it < snP; it += NW_M) {
      const unsigned qi = wl[it];
      const float4 p = sAll[NPTS + qi];
      const int cx = cellOf3(p.x), cy = cellOf3(p.y), cz = cellOf3(p.z);
      float best = wlBest[it];   // wave-uniform

      for (int r = 1; r <= 8; ++r) {
        const float cov = H3 * (float)(r - 1);
        if (best <= cov * cov) break;
        if (best > 2.0f && cov * cov >= 2.0f) break;
        const int S = (r == 1) ? 9 : 8 * r + 2 * (2 * r - 1) * (2 * r - 1);
        float b = best;
        for (int sI = lane; sI < S; sI += 64) {
          int dz, dy, xa, xb;
          if (r == 1) {
            dz = sI / 3 - 1; dy = sI % 3 - 1; xa = cx - 1; xb = cx + 1;
          } else if (sI < 8 * r) {
            if (sI < 2 * r + 1)      { dz = -r; dy = sI - r; }
            else if (sI < 4 * r + 2) { dz =  r; dy = sI - (2 * r + 1) - r; }
            else { const int t2 = sI - (4 * r + 2); dz = (t2 >> 1) - (r - 1);
                   dy = (t2 & 1) ? r : -r; }
            xa = cx - r; xb = cx + r;
          } else {
            const int t2 = sI - 8 * r, ci = t2 >> 1, w1 = 2 * r - 1;
            dz = ci / w1 - (r - 1); dy = ci % w1 - (r - 1);
            xa = xb = (t2 & 1) ? cx + r : cx - r;
          }
          const int Z = cz + dz, Y = cy + dy;
          if (Z < 0 || Z >= G3 || Y < 0 || Y >= G3) continue;
          int a3 = max(xa, 0), e3 = min(xb, G3 - 1);
          if (a3 > e3) continue;
          // branch-and-bound row prune (exact)
          const float ylo = ORG + (float)Y * H3;
          const float zlo = ORG + (float)Z * H3;
          const float dyd = fmaxf(fmaxf(ylo - p.y, p.y - (ylo + H3)), 0.f);
          const float dzd = fmaxf(fmaxf(zlo - p.z, p.z - (zlo + H3)), 0.f);
          const float dyz2 = dyd * dyd + dzd * dzd;
          const float bnd = fminf(b, 2.0f);
          if (dyz2 >= bnd) continue;
          const float halfx = sqrtf(bnd - dyz2);
          const int xlo = (int)floorf((p.x - halfx - ORG) * INVH3);
          const int xhi = (int)floorf((p.x + halfx - ORG) * INVH3);
          a3 = max(a3, xlo); e3 = min(e3, xhi);
          if (a3 > e3) continue;
          const int xs = 2 * a3, xe = 2 * e3 + 1;   // fine x-span
          unsigned js[4], je[4];
#pragma unroll
          for (int k = 0; k < 4; ++k) {
            const int zz = 2 * Z + (k >> 1), yy = 2 * Y + (k & 1);
            const int rb = (zz * G + yy) * G;
            js[k] = (rb + xs) ? ends[rb + xs - 1] : 0u;
            je[k] = ends[rb + xe];
          }
#pragma unroll
          for (int k = 0; k < 4; ++k) {
#pragma unroll 4
            for (unsigned j = js[k]; j < je[k]; ++j) {
              const float4 cd = sAll[j];
              const float dx = p.x - cd.x, dyv = p.y - cd.y, dzv = p.z - cd.z;
              b = fminf(b, fmaf(dx, dx, fmaf(dyv, dyv, dzv * dzv)));
            }
          }
        }
        for (int o = 32; o; o >>= 1) b = fminf(b, __shfl_xor(b, o, 64));
        best = b;
      }
      if (lane == 0 && best <= 2.0f) { accV += best; accC += 1.0f; }
    }
  }

  // ---- Final reduction: wave -> block -> bkt -> block 0 -> out ----
  for (int o = 32; o; o >>= 1) {
    accV += __shfl_down(accV, o, 64);
    accC += __shfl_down(accC, o, 64);
  }
  if (lane == 0) { shf[wid] = accV; shf[16 + wid] = accC; }
  __syncthreads();
  if (tid == 0) {
    float bv = 0.f, bc = 0.f;
    for (int w = 0; w < 16; ++w) { bv += shf[w]; bc += shf[16 + w]; }
    if (bc != 0.f) {
      atomicAdd(&bkt[2 * (bid & 63) + 0], bv);
      atomicAdd(&bkt[2 * (bid & 63) + 1], bc);
    }
  }
  grid.sync();
  if (bid == 0) {
    const float val = (tid < 128) ? bkt[tid] : 0.f;
    float sv = (tid & 1) ? 0.f : val;
    float cv = (tid & 1) ? val : 0.f;
    for (int o = 32; o; o >>= 1) {
      sv += __shfl_down(sv, o, 64);
      cv += __shfl_down(cv, o, 64);
    }
    if (lane == 0) { shf[wid] = sv; shf[16 + wid] = cv; }
    __syncthreads();
    if (tid == 0) {
      float S = 0.f, C = 0.f;
      for (int w = 0; w < 16; ++w) { S += shf[w]; C += shf[16 + w]; }
      out[0] = S / C;
    }
  }
}

// ===================== fallback: R3 multi-kernel pipeline =================
__global__ __launch_bounds__(BLOCK) void count_kernel(
    const float* __restrict__ pc0, const float* __restrict__ pc1,
    unsigned* __restrict__ counts0, unsigned* __restrict__ counts1) {
  const int gid = blockIdx.x * BLOCK + threadIdx.x;
  const float* p; unsigned* cnt; int i;
  if (gid < NPTS) { p = pc1; cnt = counts1; i = gid; }
  else            { p = pc0; cnt = counts0; i = gid - NPTS; }
  const float x = p[3 * i], y = p[3 * i + 1], z = p[3 * i + 2];
  atomicAdd(&cnt[(cellOf(z) * G + cellOf(y)) * G + cellOf(x)], 1u);
}

__global__ __launch_bounds__(1024) void scan_partial_kernel(
    const unsigned* __restrict__ counts0, const unsigned* __restrict__ counts1,
    unsigned* __restrict__ partials) {
  const unsigned* counts = blockIdx.y ? counts0 : counts1;
  const int base = blockIdx.x * CHUNK + threadIdx.x * 2;
  unsigned sum = counts[base] + counts[base + 1];
  for (int o = 32; o; o >>= 1) sum += __shfl_down(sum, o, 64);
  __shared__ unsigned ws[16];
  if ((threadIdx.x & 63) == 0) ws[threadIdx.x >> 6] = sum;
  __syncthreads();
  if (threadIdx.x == 0) {
    unsigned t = 0;
    for (int w = 0; w < 16; ++w) t += ws[w];
    partials[blockIdx.y * SB + blockIdx.x] = t;
  }
}

__global__ __launch_bounds__(256) void scan_mid_kernel(
    unsigned* __restrict__ partials) {
  const int tid = threadIdx.x;
  const int g   = tid >> 7;
  const int li  = tid & 127;
  const unsigned v = partials[g * SB + li];
  unsigned inc = v;
  for (int o = 1; o < 64; o <<= 1) {
    const unsigned t = __shfl_up(inc, o, 64);
    if ((tid & 63) >= o) inc += t;
  }
  __shared__ unsigned wt[4];
  if ((tid & 63) == 63) wt[tid >> 6] = inc;
  __syncthreads();
  const unsigned woff = ((tid >> 6) & 1) ? wt[g << 1] : 0u;
  partials[g * SB + li] = woff + inc - v;
}

__global__ __launch_bounds__(1024) void scan_final_kernel(
    const unsigned* __restrict__ counts0, unsigned* __restrict__ cur0,
    const unsigned* __restrict__ counts1, unsigned* __restrict__ cur1,
    const unsigned* __restrict__ partials) {
  const unsigned* counts = blockIdx.y ? counts0 : counts1;
  unsigned* cur          = blockIdx.y ? cur0    : cur1;
  const int tid = threadIdx.x;
  const int base = blockIdx.x * CHUNK + tid * 2;
  const unsigned a = counts[base], b = counts[base + 1];
  const unsigned tsum = a + b;
  unsigned inc = tsum;
  for (int o = 1; o < 64; o <<= 1) {
    const unsigned t = __shfl_up(inc, o, 64);
    if ((tid & 63) >= o) inc += t;
  }
  __shared__ unsigned wt[16];
  if ((tid & 63) == 63) wt[tid >> 6] = inc;
  __syncthreads();
  if (tid < 16) {
    unsigned w = wt[tid];
    for (int o = 1; o < 16; o <<= 1) {
      const unsigned t = __shfl_up(w, o, 16);
      if (tid >= o) w += t;
    }
    wt[tid] = w;
  }
  __syncthreads();
  const unsigned woff = (tid >> 6) ? wt[(tid >> 6) - 1] : 0u;
  const unsigned off =
      partials[blockIdx.y * SB + blockIdx.x] + woff + inc - tsum;
  cur[base] = off;
  cur[base + 1] = off + a;
}

__global__ __launch_bounds__(BLOCK) void scatter_kernel(
    const float* __restrict__ pc0, const float* __restrict__ pc1,
    unsigned* __restrict__ cur0, unsigned* __restrict__ cur1,
    float4* __restrict__ q, float4* __restrict__ s) {
  const int gid = blockIdx.x * BLOCK + threadIdx.x;
  const float* p; unsigned* cur; float4* dst; int i;
  if (gid < NPTS) { p = pc1; cur = cur1; dst = s; i = gid; }
  else            { p = pc0; cur = cur0; dst = q; i = gid - NPTS; }
  const float x = p[3 * i], y = p[3 * i + 1], z = p[3 * i + 2];
  const int cid = (cellOf(z) * G + cellOf(y)) * G + cellOf(x);
  dst[atomicAdd(&cur[cid], 1u)] = make_float4(x, y, z, 0.f);
}

__global__ __launch_bounds__(BLOCK) void query_kernel(
    const float4* __restrict__ q, const unsigned* __restrict__ ends,
    const float4* __restrict__ s,
    unsigned* __restrict__ wl, float* __restrict__ wlBest,
    unsigned* __restrict__ pendCnt, float* __restrict__ bkt) {
  const int gtid = blockIdx.x * BLOCK + threadIdx.x;
  const int i   = gtid >> 2;
  const int sub = gtid & 3;
  const float4 p = q[i];
  const int cx = cellOf(p.x), cy = cellOf(p.y), cz = cellOf(p.z);
  const int x0 = max(cx - 1, 0), x1 = min(cx + 1, G - 1);

  unsigned rs[9], re[9];
#pragma unroll
  for (int rr = 0; rr < 9; ++rr) {
    const int zz = cz + rr / 3 - 1, yy = cy + rr % 3 - 1;
    const bool ok = (zz >= 0) && (zz < G) && (yy >= 0) && (yy < G);
    const int rb = ok ? (zz * G + yy) * G : 0;
    rs[rr] = ok ? ((rb + x0) ? ends[rb + x0 - 1] : 0u) : 0u;
    re[rr] = ok ? ends[rb + x1] : 0u;
  }
  float best = 3.4e38f;
#pragma unroll
  for (int rr = 0; rr < 9; ++rr) {
#pragma unroll 4
    for (unsigned j = rs[rr] + sub; j < re[rr]; j += 4) {
      const float4 c = s[j];
      const float dx = p.x - c.x, dy = p.y - c.y, dz = p.z - c.z;
      best = fminf(best, fmaf(dx, dx, fmaf(dy, dy, dz * dz)));
    }
  }
  best = fminf(best, __shfl_xor(best, 1, 64));
  best = fminf(best, __shfl_xor(best, 2, 64));

  float v = 0.f, c = 0.f;
  if (sub == 0) {
    if (best > H * H) {
      const unsigned k = atomicAdd(pendCnt, 1u);
      wl[k] = (unsigned)i; wlBest[k] = best;
    } else if (best <= 2.0f) { v = best; c = 1.0f; }
  }

  for (int o = 32; o; o >>= 1) {
    v += __shfl_down(v, o, 64);
    c += __shfl_down(c, o, 64);
  }
  __shared__ float wsum[BLOCK / 64], wcnt[BLOCK / 64];
  const int wid = threadIdx.x >> 6;
  if ((threadIdx.x & 63) == 0) { wsum[wid] = v; wcnt[wid] = c; }
  __syncthreads();
  if (threadIdx.x == 0) {
    float bv = 0.f, bc = 0.f;
    for (int w = 0; w < BLOCK / 64; ++w) { bv += wsum[w]; bc += wcnt[w]; }
    if (bc != 0.f) {
      atomicAdd(&bkt[2 * (blockIdx.x & 63) + 0], bv);
      atomicAdd(&bkt[2 * (blockIdx.x & 63) + 1], bc);
    }
  }
}

__global__ __launch_bounds__(BLOCK) void pending_kernel(
    const float4* __restrict__ q,
    const unsigned* __restrict__ ends, const float4* __restrict__ s,
    const unsigned* __restrict__ wl, const float* __restrict__ wlBest,
    unsigned* __restrict__ pendCnt, float* __restrict__ bkt,
    unsigned* __restrict__ done, float* __restrict__ out) {
  __shared__ int snP;
  __shared__ float wsum[BLOCK / 64], wcnt[BLOCK / 64];
  __shared__ int isLast;
  __shared__ float fs[BLOCK / 64], fc[BLOCK / 64];
  if (threadIdx.x == 0) snP = (int)atomicAdd(pendCnt, 0u);
  __syncthreads();
  const int lane = threadIdx.x & 63, wid = threadIdx.x >> 6;
  const int gw = blockIdx.x * (BLOCK / 64) + wid;
  const int nW = PBLOCKS * (BLOCK / 64);
  float v = 0.f, c = 0.f;

  for (int it = gw; it < snP; it += nW) {
    const unsigned qi = wl[it];
    const float4 p = q[qi];
    const int cx = cellOf3(p.x), cy = cellOf3(p.y), cz = cellOf3(p.z);
    float best = wlBest[it];

    for (int r = 1; r <= 8; ++r) {
      const float cov = H3 * (float)(r - 1);
      if (best <= cov * cov) break;
      if (best > 2.0f && cov * cov >= 2.0f) break;
      const int S = (r == 1) ? 9 : 8 * r + 2 * (2 * r - 1) * (2 * r - 1);
      float b = best;
      for (int sI = lane; sI < S; sI += 64) {
        int dz, dy, xa, xb;
        if (r == 1) {
          dz = sI / 3 - 1; dy = sI % 3 - 1; xa = cx - 1; xb = cx + 1;
        } else if (sI < 8 * r) {
          if (sI < 2 * r + 1)      { dz = -r; dy = sI - r; }
          else if (sI < 4 * r + 2) { dz =  r; dy = sI - (2 * r + 1) - r; }
          else { const int t2 = sI - (4 * r + 2); dz = (t2 >> 1) - (r - 1);
                 dy = (t2 & 1) ? r : -r; }
          xa = cx - r; xb = cx + r;
        } else {
          const int t2 = sI - 8 * r, ci = t2 >> 1, w1 = 2 * r - 1;
          dz = ci / w1 - (r - 1); dy = ci % w1 - (r - 1);
          xa = xb = (t2 & 1) ? cx + r : cx - r;
        }
        const int Z = cz + dz, Y = cy + dy;
        if (Z < 0 || Z >= G3 || Y < 0 || Y >= G3) continue;
        int a3 = max(xa, 0), e3 = min(xb, G3 - 1);
        if (a3 > e3) continue;
        const float ylo = ORG + (float)Y * H3;
        const float zlo = ORG + (float)Z * H3;
        const float dyd = fmaxf(fmaxf(ylo - p.y, p.y - (ylo + H3)), 0.f);
        const float dzd = fmaxf(fmaxf(zlo - p.z, p.z - (zlo + H3)), 0.f);
        const float dyz2 = dyd * dyd + dzd * dzd;
        const float bnd = fminf(b, 2.0f);
        if (dyz2 >= bnd) continue;
        const float halfx = sqrtf(bnd - dyz2);
        const int xlo = (int)floorf((p.x - halfx - ORG) * INVH3);
        const int xhi = (int)floorf((p.x + halfx - ORG) * INVH3);
        a3 = max(a3, xlo); e3 = min(e3, xhi);
        if (a3 > e3) continue;
        const int xs = 2 * a3, xe = 2 * e3 + 1;
        unsigned js[4], je[4];
#pragma unroll
        for (int k = 0; k < 4; ++k) {
          const int zz = 2 * Z + (k >> 1), yy = 2 * Y + (k & 1);
          const int rb = (zz * G + yy) * G;
          js[k] = (rb + xs) ? ends[rb + xs - 1] : 0u;
          je[k] = ends[rb + xe];
        }
#pragma unroll
        for (int k = 0; k < 4; ++k) {
#pragma unroll 4
          for (unsigned j = js[k]; j < je[k]; ++j) {
            const float4 cd = s[j];
            const float dx = p.x - cd.x, dyv = p.y - cd.y, dzv = p.z - cd.z;
            b = fminf(b, fmaf(dx, dx, fmaf(dyv, dyv, dzv * dzv)));
          }
        }
      }
      for (int o = 32; o; o >>= 1) b = fminf(b, __shfl_xor(b, o, 64));
      best = b;
    }
    if (lane == 0 && best <= 2.0f) { v += best; c += 1.0f; }
  }

  if (lane == 0) { wsum[wid] = v; wcnt[wid] = c; }
  __syncthreads();
  if (threadIdx.x == 0) {
    float bv = 0.f, bc = 0.f;
    for (int w = 0; w < BLOCK / 64; ++w) { bv += wsum[w]; bc += wcnt[w]; }
    if (bc != 0.f) {
      atomicAdd(&bkt[2 * (blockIdx.x & 63) + 0], bv);
      atomicAdd(&bkt[2 * (blockIdx.x & 63) + 1], bc);
    }
    __threadfence();
    isLast = (atomicAdd(done, 1u) == (unsigned)(PBLOCKS - 1));
  }
  __syncthreads();
  if (isLast) {
    const float val = (threadIdx.x < 128) ? atomicAdd(&bkt[threadIdx.x], 0.0f) : 0.0f;
    float sv = (threadIdx.x & 1) ? 0.f : val;
    float cv = (threadIdx.x & 1) ? val : 0.f;
    for (int o = 32; o; o >>= 1) {
      sv += __shfl_down(sv, o, 64);
      cv += __shfl_down(cv, o, 64);
    }
    if (lane == 0) { fs[wid] = sv; fc[wid] = cv; }
    __syncthreads();
    if (threadIdx.x == 0) {
      float S = 0.f, C = 0.f;
      for (int w = 0; w < BLOCK / 64; ++w) { S += fs[w]; C += fc[w]; }
      out[0] = S / C;
    }
  }
}

extern "C" void kernel_launch(void* const* d_in, const int* in_sizes, int n_in,
                              void* d_out, int out_size, void* d_ws, size_t ws_size,
                              hipStream_t stream) {
  const float* pc0 = (const float*)d_in[0];
  const float* pc1 = (const float*)d_in[1];
  float* out = (float*)d_out;

  // Shared slab layout (R3-compatible). NC*4 and NPTS*16 are 256-aligned, so
  // counts1|counts0, cur1|cur0, s|q are contiguous pairs = mega's unified
  // countsAll / curAll / sAll.
  char* w = (char*)d_ws;
  auto nxt = [&](size_t bytes) {
    char* p = w; w += (bytes + 255) & ~(size_t)255; return p;
  };
  unsigned* counts1  = (unsigned*)nxt((size_t)NC * 4);           // 1 MB
  unsigned* counts0  = (unsigned*)nxt((size_t)NC * 4);           // 1 MB
  char*     misc     = nxt(1024);   // bkt[128] | done | pendCnt
  float*    bkt      = (float*)misc;
  unsigned* done     = (unsigned*)(misc + 512);
  unsigned* pendCnt  = (unsigned*)(misc + 516);
  unsigned* partials = (unsigned*)nxt((size_t)2 * SB * 4);       // 256 entries
  unsigned* cur1     = (unsigned*)nxt((size_t)NC * 4);           // 1 MB
  unsigned* cur0     = (unsigned*)nxt((size_t)NC * 4);           // 1 MB
  float4*   s        = (float4*)nxt((size_t)NPTS * 16);          // 1 MB
  float4*   q        = (float4*)nxt((size_t)NPTS * 16);          // 1 MB
  unsigned* wl       = (unsigned*)nxt((size_t)NPTS * 4);         // 256 KB
  float*    wlBest   = (float*)nxt((size_t)NPTS * 4);            // 256 KB

  unsigned* countsAll = counts1;   // counts1 | counts0
  unsigned* curAll    = cur1;      // cur1 | cur0
  float4*   sAll      = s;         // s | q

  void* args[] = { &pc0, &pc1, &countsAll, &curAll, &partials, &sAll,
                   &wl, &wlBest, &pendCnt, &bkt, &out };
  hipError_t ce = hipLaunchCooperativeKernel((void*)mega_kernel, dim3(GRID_M),
                                             dim3(BLOCK_M), args, 0, stream);
  if (ce != hipSuccess) {
    // Fallback: verified R3 pipeline (139.1us).
    hipMemsetAsync(counts1, 0, (size_t)2 * NC * 4 + 1024, stream);
    count_kernel<<<2 * NPTS / BLOCK, BLOCK, 0, stream>>>(pc0, pc1, counts0, counts1);
    scan_partial_kernel<<<dim3(SB, 2), 1024, 0, stream>>>(counts0, counts1, partials);
    scan_mid_kernel<<<1, 256, 0, stream>>>(partials);
    scan_final_kernel<<<dim3(SB, 2), 1024, 0, stream>>>(counts0, cur0,
                                                        counts1, cur1, partials);
    scatter_kernel<<<2 * NPTS / BLOCK, BLOCK, 0, stream>>>(
        pc0, pc1, cur0, cur1, q, s);
    query_kernel<<<4 * NPTS / BLOCK, BLOCK, 0, stream>>>(q, cur1, s, wl, wlBest,
                                                         pendCnt, bkt);
    pending_kernel<<<PBLOCKS, BLOCK, 0, stream>>>(q, cur1, s, wl, wlBest,
                                                  pendCnt, bkt, done, out);
  }
}

// Round 7
// 146.439 us; speedup vs baseline: 2.2486x; 2.2486x over previous
//
#include <hip/hip_runtime.h>

// Chamfer forward: dist0[i] = min_j ||pc0[i]-pc1[j]||^2 ; out = mean(dist0[dist0<=2])
// N = M = 65536 i.i.d. N(0,1)^3 points, fp32.
// R7 = REVERT to R3 multi-kernel pipeline (verified 139.1us) + ONE change:
// query_kernel 4 -> 8 sublanes per query (grid 1024 -> 2048 blocks).
// R6 post-mortem: cooperative mega-kernel ran at 262us (vs 139 pipeline) --
// fusion loses: 1 block/CU caps occupancy at 16 waves/CU on the latency-bound
// phases and 9 grid.sync()s (device-scope rendezvous across 8 XCDs) eat the
// launch-gap savings. Multi-kernel pipeline is the platform going forward.
// Query rationale: still the largest dispatch (~38us), latency-bound with avg
// ~62 candidates/query; 8 sublanes halves the serial chain (~8 cand/lane) and
// doubles waves to 8192 (32/CU cap). Range loads replicate 8x but are
// independent overlapped L2 hits.

constexpr int   NPTS  = 65536;
constexpr int   G     = 64;
constexpr int   NC    = G * G * G;    // 262144 fine cells
constexpr float H     = 0.125f;
constexpr float ORG   = -4.0f;
constexpr float INVH  = 8.0f;
constexpr int   G3    = 32;           // medium geometry (phase 2 rings)
constexpr float H3    = 0.25f;
constexpr float INVH3 = 4.0f;
constexpr int   BLOCK = 256;
constexpr int   PBLOCKS = 1024;       // pending grid: 4096 waves >= pending count
constexpr int   SB    = 128;          // scan blocks per fine array
constexpr int   CHUNK = NC / SB;      // 2048 counts per scan block (2/thread)

__device__ __forceinline__ int cellOf(float x) {
  int c = (int)floorf((x - ORG) * INVH);
  return min(max(c, 0), G - 1);
}
__device__ __forceinline__ int cellOf3(float x) {
  int c = (int)floorf((x - ORG) * INVH3);
  return min(max(c, 0), G3 - 1);
}

__global__ __launch_bounds__(BLOCK) void count_kernel(
    const float* __restrict__ pc0, const float* __restrict__ pc1,
    unsigned* __restrict__ counts0, unsigned* __restrict__ counts1) {
  const int gid = blockIdx.x * BLOCK + threadIdx.x;
  const float* p; unsigned* cnt; int i;
  if (gid < NPTS) { p = pc1; cnt = counts1; i = gid; }
  else            { p = pc0; cnt = counts0; i = gid - NPTS; }
  const float x = p[3 * i], y = p[3 * i + 1], z = p[3 * i + 2];
  atomicAdd(&cnt[(cellOf(z) * G + cellOf(y)) * G + cellOf(x)], 1u);
}

// Phase A: per-block partial sums. grid=(SB,2); y=0->counts1, y=1->counts0.
__global__ __launch_bounds__(1024) void scan_partial_kernel(
    const unsigned* __restrict__ counts0, const unsigned* __restrict__ counts1,
    unsigned* __restrict__ partials) {
  const unsigned* counts = blockIdx.y ? counts0 : counts1;
  const int base = blockIdx.x * CHUNK + threadIdx.x * 2;
  unsigned sum = counts[base] + counts[base + 1];
  for (int o = 32; o; o >>= 1) sum += __shfl_down(sum, o, 64);
  __shared__ unsigned ws[16];
  if ((threadIdx.x & 63) == 0) ws[threadIdx.x >> 6] = sum;
  __syncthreads();
  if (threadIdx.x == 0) {
    unsigned t = 0;
    for (int w = 0; w < 16; ++w) t += ws[w];
    partials[blockIdx.y * SB + blockIdx.x] = t;
  }
}

// Phase B: one 256-thread block exclusively scans both 128-entry partial arrays.
__global__ __launch_bounds__(256) void scan_mid_kernel(
    unsigned* __restrict__ partials) {
  const int tid = threadIdx.x;
  const int g   = tid >> 7;
  const int li  = tid & 127;
  const unsigned v = partials[g * SB + li];
  unsigned inc = v;
  for (int o = 1; o < 64; o <<= 1) {
    const unsigned t = __shfl_up(inc, o, 64);
    if ((tid & 63) >= o) inc += t;
  }
  __shared__ unsigned wt[4];
  if ((tid & 63) == 63) wt[tid >> 6] = inc;
  __syncthreads();
  const unsigned woff = ((tid >> 6) & 1) ? wt[g << 1] : 0u;
  partials[g * SB + li] = woff + inc - v;
}

// Phase C: block scan + offset -> cur (CSR starts). grid=(SB,2).
__global__ __launch_bounds__(1024) void scan_final_kernel(
    const unsigned* __restrict__ counts0, unsigned* __restrict__ cur0,
    const unsigned* __restrict__ counts1, unsigned* __restrict__ cur1,
    const unsigned* __restrict__ partials) {
  const unsigned* counts = blockIdx.y ? counts0 : counts1;
  unsigned* cur          = blockIdx.y ? cur0    : cur1;
  const int tid = threadIdx.x;
  const int base = blockIdx.x * CHUNK + tid * 2;
  const unsigned a = counts[base], b = counts[base + 1];
  const unsigned tsum = a + b;
  unsigned inc = tsum;
  for (int o = 1; o < 64; o <<= 1) {
    const unsigned t = __shfl_up(inc, o, 64);
    if ((tid & 63) >= o) inc += t;
  }
  __shared__ unsigned wt[16];
  if ((tid & 63) == 63) wt[tid >> 6] = inc;
  __syncthreads();
  if (tid < 16) {
    unsigned w = wt[tid];
    for (int o = 1; o < 16; o <<= 1) {
      const unsigned t = __shfl_up(w, o, 16);
      if (tid >= o) w += t;
    }
    wt[tid] = w;
  }
  __syncthreads();
  const unsigned woff = (tid >> 6) ? wt[(tid >> 6) - 1] : 0u;
  const unsigned off =
      partials[blockIdx.y * SB + blockIdx.x] + woff + inc - tsum;
  cur[base] = off;
  cur[base + 1] = off + a;
}

// After scatter, cur[c] = CSR inclusive end of cell c (start = cur[c-1]).
__global__ __launch_bounds__(BLOCK) void scatter_kernel(
    const float* __restrict__ pc0, const float* __restrict__ pc1,
    unsigned* __restrict__ cur0, unsigned* __restrict__ cur1,
    float4* __restrict__ q, float4* __restrict__ s) {
  const int gid = blockIdx.x * BLOCK + threadIdx.x;
  const float* p; unsigned* cur; float4* dst; int i;
  if (gid < NPTS) { p = pc1; cur = cur1; dst = s; i = gid; }
  else            { p = pc0; cur = cur0; dst = q; i = gid - NPTS; }
  const float x = p[3 * i], y = p[3 * i + 1], z = p[3 * i + 2];
  const int cid = (cellOf(z) * G + cellOf(y)) * G + cellOf(x);
  dst[atomicAdd(&cur[cid], 1u)] = make_float4(x, y, z, 0.f);
}

// Phase 1: fine rings 0..1, 8 lanes per query; push unfinished to worklist.
__global__ __launch_bounds__(BLOCK) void query_kernel(
    const float4* __restrict__ q, const unsigned* __restrict__ ends,
    const float4* __restrict__ s,
    unsigned* __restrict__ wl, float* __restrict__ wlBest,
    unsigned* __restrict__ pendCnt, float* __restrict__ bkt) {
  const int gtid = blockIdx.x * BLOCK + threadIdx.x;
  const int i   = gtid >> 3;        // query index
  const int sub = gtid & 7;         // sub-lane (8 per query)
  const float4 p = q[i];
  const int cx = cellOf(p.x), cy = cellOf(p.y), cz = cellOf(p.z);
  const int x0 = max(cx - 1, 0), x1 = min(cx + 1, G - 1);

  unsigned rs[9], re[9];
#pragma unroll
  for (int rr = 0; rr < 9; ++rr) {
    const int zz = cz + rr / 3 - 1, yy = cy + rr % 3 - 1;
    const bool ok = (zz >= 0) && (zz < G) && (yy >= 0) && (yy < G);
    const int rb = ok ? (zz * G + yy) * G : 0;
    rs[rr] = ok ? ((rb + x0) ? ends[rb + x0 - 1] : 0u) : 0u;
    re[rr] = ok ? ends[rb + x1] : 0u;
  }
  float best = 3.4e38f;
#pragma unroll
  for (int rr = 0; rr < 9; ++rr) {
#pragma unroll 4
    for (unsigned j = rs[rr] + sub; j < re[rr]; j += 8) {
      const float4 c = s[j];
      const float dx = p.x - c.x, dy = p.y - c.y, dz = p.z - c.z;
      best = fminf(best, fmaf(dx, dx, fmaf(dy, dy, dz * dz)));
    }
  }
  // combine the 8 sub-lanes (lanes i*8 .. i*8+7 are in the same wave)
  best = fminf(best, __shfl_xor(best, 1, 64));
  best = fminf(best, __shfl_xor(best, 2, 64));
  best = fminf(best, __shfl_xor(best, 4, 64));

  float v = 0.f, c = 0.f;
  if (sub == 0) {
    if (best > H * H) {            // not provably exact -> phase 2
      const unsigned k = atomicAdd(pendCnt, 1u);
      wl[k] = (unsigned)i; wlBest[k] = best;
    } else if (best <= 2.0f) { v = best; c = 1.0f; }
  }

  for (int o = 32; o; o >>= 1) {
    v += __shfl_down(v, o, 64);
    c += __shfl_down(c, o, 64);
  }
  __shared__ float wsum[BLOCK / 64], wcnt[BLOCK / 64];
  const int wid = threadIdx.x >> 6;
  if ((threadIdx.x & 63) == 0) { wsum[wid] = v; wcnt[wid] = c; }
  __syncthreads();
  if (threadIdx.x == 0) {
    float bv = 0.f, bc = 0.f;
    for (int w = 0; w < BLOCK / 64; ++w) { bv += wsum[w]; bc += wcnt[w]; }
    if (bc != 0.f) {
      atomicAdd(&bkt[2 * (blockIdx.x & 63) + 0], bv);
      atomicAdd(&bkt[2 * (blockIdx.x & 63) + 1], bc);
    }
  }
}

// Phase 2: one wave per pending query; MEDIUM ring geometry over the FINE CSR
// (one medium row = 4 fine rows). Ring 1 = full 3x3x3 medium; r=8 head always
// terminates. Branch-and-bound row prune (box y/z distance + x-span clip to
// the ball of radius sqrt(min(b,2)) around p) -- exact, verified R3.
__global__ __launch_bounds__(BLOCK) void pending_kernel(
    const float4* __restrict__ q,
    const unsigned* __restrict__ ends, const float4* __restrict__ s,
    const unsigned* __restrict__ wl, const float* __restrict__ wlBest,
    unsigned* __restrict__ pendCnt, float* __restrict__ bkt,
    unsigned* __restrict__ done, float* __restrict__ out) {
  __shared__ int snP;
  __shared__ float wsum[BLOCK / 64], wcnt[BLOCK / 64];
  __shared__ int isLast;
  __shared__ float fs[BLOCK / 64], fc[BLOCK / 64];
  if (threadIdx.x == 0) snP = (int)atomicAdd(pendCnt, 0u);
  __syncthreads();
  const int lane = threadIdx.x & 63, wid = threadIdx.x >> 6;
  const int gw = blockIdx.x * (BLOCK / 64) + wid;
  const int nW = PBLOCKS * (BLOCK / 64);
  float v = 0.f, c = 0.f;

  for (int it = gw; it < snP; it += nW) {
    const unsigned qi = wl[it];
    const float4 p = q[qi];
    const int cx = cellOf3(p.x), cy = cellOf3(p.y), cz = cellOf3(p.z);
    float best = wlBest[it];   // wave-uniform (same address)

    for (int r = 1; r <= 8; ++r) {
      const float cov = H3 * (float)(r - 1);    // unscanned dist lower bound
      if (best <= cov * cov) break;             // exact
      if (best > 2.0f && cov * cov >= 2.0f) break;  // masked out either way
      const int S = (r == 1) ? 9 : 8 * r + 2 * (2 * r - 1) * (2 * r - 1);
      float b = best;
      for (int sI = lane; sI < S; sI += 64) {
        int dz, dy, xa, xb;
        if (r == 1) {                           // full 3x3x3 medium rows
          dz = sI / 3 - 1; dy = sI % 3 - 1; xa = cx - 1; xb = cx + 1;
        } else if (sI < 8 * r) {                // shell faces: full x rows
          if (sI < 2 * r + 1)      { dz = -r; dy = sI - r; }
          else if (sI < 4 * r + 2) { dz =  r; dy = sI - (2 * r + 1) - r; }
          else { const int t2 = sI - (4 * r + 2); dz = (t2 >> 1) - (r - 1);
                 dy = (t2 & 1) ? r : -r; }
          xa = cx - r; xb = cx + r;
        } else {                                // interior rows: x = +/- r ends
          const int t2 = sI - 8 * r, ci = t2 >> 1, w1 = 2 * r - 1;
          dz = ci / w1 - (r - 1); dy = ci % w1 - (r - 1);
          xa = xb = (t2 & 1) ? cx + r : cx - r;
        }
        const int Z = cz + dz, Y = cy + dy;
        if (Z < 0 || Z >= G3 || Y < 0 || Y >= G3) continue;
        int a3 = max(xa, 0), e3 = min(xb, G3 - 1);
        if (a3 > e3) continue;
        // --- branch-and-bound row prune (exact) -------------------------
        const float ylo = ORG + (float)Y * H3;
        const float zlo = ORG + (float)Z * H3;
        const float dyd = fmaxf(fmaxf(ylo - p.y, p.y - (ylo + H3)), 0.f);
        const float dzd = fmaxf(fmaxf(zlo - p.z, p.z - (zlo + H3)), 0.f);
        const float dyz2 = dyd * dyd + dzd * dzd;
        const float bnd = fminf(b, 2.0f);
        if (dyz2 >= bnd) continue;
        const float halfx = sqrtf(bnd - dyz2);
        const int xlo = (int)floorf((p.x - halfx - ORG) * INVH3);
        const int xhi = (int)floorf((p.x + halfx - ORG) * INVH3);
        a3 = max(a3, xlo); e3 = min(e3, xhi);
        if (a3 > e3) continue;
        // ----------------------------------------------------------------
        const int xs = 2 * a3, xe = 2 * e3 + 1; // fine x-span
        // 4 fine rows per medium row; ranges preloaded (independent loads)
        unsigned js[4], je[4];
#pragma unroll
        for (int k = 0; k < 4; ++k) {
          const int zz = 2 * Z + (k >> 1), yy = 2 * Y + (k & 1);
          const int rb = (zz * G + yy) * G;
          js[k] = (rb + xs) ? ends[rb + xs - 1] : 0u;
          je[k] = ends[rb + xe];
        }
#pragma unroll
        for (int k = 0; k < 4; ++k) {
#pragma unroll 4
          for (unsigned j = js[k]; j < je[k]; ++j) {
            const float4 cd = s[j];
            const float dx = p.x - cd.x, dyv = p.y - cd.y, dzv = p.z - cd.z;
            b = fminf(b, fmaf(dx, dx, fmaf(dyv, dyv, dzv * dzv)));
          }
        }
      }
      for (int o = 32; o; o >>= 1) b = fminf(b, __shfl_xor(b, o, 64));
      best = b;                                 // wave-uniform again
    }
    if (lane == 0 && best <= 2.0f) { v += best; c += 1.0f; }
  }

  if (lane == 0) { wsum[wid] = v; wcnt[wid] = c; }
  __syncthreads();
  if (threadIdx.x == 0) {
    float bv = 0.f, bc = 0.f;
    for (int w = 0; w < BLOCK / 64; ++w) { bv += wsum[w]; bc += wcnt[w]; }
    if (bc != 0.f) {
      atomicAdd(&bkt[2 * (blockIdx.x & 63) + 0], bv);
      atomicAdd(&bkt[2 * (blockIdx.x & 63) + 1], bc);
    }
    __threadfence();
    isLast = (atomicAdd(done, 1u) == (unsigned)(PBLOCKS - 1));
  }
  __syncthreads();
  if (isLast) {   // parallel coherent read of the 128 bucket slots + reduce
    const float val = (threadIdx.x < 128) ? atomicAdd(&bkt[threadIdx.x], 0.0f) : 0.0f;
    float sv = (threadIdx.x & 1) ? 0.f : val;
    float cv = (threadIdx.x & 1) ? val : 0.f;
    for (int o = 32; o; o >>= 1) {
      sv += __shfl_down(sv, o, 64);
      cv += __shfl_down(cv, o, 64);
    }
    if (lane == 0) { fs[wid] = sv; fc[wid] = cv; }
    __syncthreads();
    if (threadIdx.x == 0) {
      float S = 0.f, C = 0.f;
      for (int w = 0; w < BLOCK / 64; ++w) { S += fs[w]; C += fc[w]; }
      out[0] = S / C;
    }
  }
}

extern "C" void kernel_launch(void* const* d_in, const int* in_sizes, int n_in,
                              void* d_out, int out_size, void* d_ws, size_t ws_size,
                              hipStream_t stream) {
  const float* pc0 = (const float*)d_in[0];
  const float* pc1 = (const float*)d_in[1];
  float* out = (float*)d_out;

  // slab carve-up; counts1|counts0|misc contiguous -> single memset
  char* w = (char*)d_ws;
  auto nxt = [&](size_t bytes) {
    char* p = w; w += (bytes + 255) & ~(size_t)255; return p;
  };
  unsigned* counts1  = (unsigned*)nxt((size_t)NC * 4);           // 1 MB
  unsigned* counts0  = (unsigned*)nxt((size_t)NC * 4);           // 1 MB
  char*     misc     = nxt(1024);   // bkt[128] | done | pendCnt
  float*    bkt      = (float*)misc;
  unsigned* done     = (unsigned*)(misc + 512);
  unsigned* pendCnt  = (unsigned*)(misc + 516);
  unsigned* partials = (unsigned*)nxt((size_t)2 * SB * 4);       // 1 KB
  unsigned* cur1     = (unsigned*)nxt((size_t)NC * 4);           // 1 MB
  unsigned* cur0     = (unsigned*)nxt((size_t)NC * 4);           // 1 MB
  float4*   s        = (float4*)nxt((size_t)NPTS * 16);          // 1 MB
  float4*   q        = (float4*)nxt((size_t)NPTS * 16);          // 1 MB
  unsigned* wl       = (unsigned*)nxt((size_t)NPTS * 4);         // 256 KB
  float*    wlBest   = (float*)nxt((size_t)NPTS * 4);            // 256 KB

  hipMemsetAsync(counts1, 0, (size_t)2 * NC * 4 + 1024, stream);

  count_kernel<<<2 * NPTS / BLOCK, BLOCK, 0, stream>>>(pc0, pc1, counts0, counts1);
  scan_partial_kernel<<<dim3(SB, 2), 1024, 0, stream>>>(counts0, counts1, partials);
  scan_mid_kernel<<<1, 256, 0, stream>>>(partials);
  scan_final_kernel<<<dim3(SB, 2), 1024, 0, stream>>>(counts0, cur0,
                                                      counts1, cur1, partials);
  scatter_kernel<<<2 * NPTS / BLOCK, BLOCK, 0, stream>>>(
      pc0, pc1, cur0, cur1, q, s);
  query_kernel<<<8 * NPTS / BLOCK, BLOCK, 0, stream>>>(q, cur1, s, wl, wlBest,
                                                       pendCnt, bkt);
  pending_kernel<<<PBLOCKS, BLOCK, 0, stream>>>(q, cur1, s, wl, wlBest,
                                                pendCnt, bkt, done, out);
}

// Round 8
// 136.627 us; speedup vs baseline: 2.4101x; 1.0718x over previous
//
#include <hip/hip_runtime.h>

// Chamfer forward: dist0[i] = min_j ||pc0[i]-pc1[j]||^2 ; out = mean(dist0[dist0<=2])
// N = M = 65536 i.i.d. N(0,1)^3 points, fp32.
// R8 = R3 base (139.1us verified: 4-sublane query, pending w/ branch-and-bound
// prune) + ONE change: per-point BOX-DISTANCE exactness bound in query.
// R7 post-mortem: 8 sublanes regressed (+7.3us) -- per-sublane setup (18 range
// loads, reductions) scales with replication while chain-shortening saturated
// at 4. Sublane knob mapped: 4 is optimal. Reverted.
// New bound: query is exact iff best <= dbox^2 where dbox = distance from p to
// the unscanned exterior of the scanned 3x3x3 fine box (dbox in [H,2H]; domain-
// clamped faces are +inf since clamping means no points beyond them). Replaces
// the worst-case H^2. Est. pending count 3800 -> ~1100 (removes near-threshold
// items + their wl atomics). Exact: any unscanned point is >= dbox away.

constexpr int   NPTS  = 65536;
constexpr int   G     = 64;
constexpr int   NC    = G * G * G;    // 262144 fine cells
constexpr float H     = 0.125f;
constexpr float ORG   = -4.0f;
constexpr float INVH  = 8.0f;
constexpr int   G3    = 32;           // medium geometry (phase 2 rings)
constexpr float H3    = 0.25f;
constexpr float INVH3 = 4.0f;
constexpr int   BLOCK = 256;
constexpr int   PBLOCKS = 1024;       // pending grid: 4096 waves >= pending count
constexpr int   SB    = 128;          // scan blocks per fine array
constexpr int   CHUNK = NC / SB;      // 2048 counts per scan block (2/thread)

__device__ __forceinline__ int cellOf(float x) {
  int c = (int)floorf((x - ORG) * INVH);
  return min(max(c, 0), G - 1);
}
__device__ __forceinline__ int cellOf3(float x) {
  int c = (int)floorf((x - ORG) * INVH3);
  return min(max(c, 0), G3 - 1);
}

__global__ __launch_bounds__(BLOCK) void count_kernel(
    const float* __restrict__ pc0, const float* __restrict__ pc1,
    unsigned* __restrict__ counts0, unsigned* __restrict__ counts1) {
  const int gid = blockIdx.x * BLOCK + threadIdx.x;
  const float* p; unsigned* cnt; int i;
  if (gid < NPTS) { p = pc1; cnt = counts1; i = gid; }
  else            { p = pc0; cnt = counts0; i = gid - NPTS; }
  const float x = p[3 * i], y = p[3 * i + 1], z = p[3 * i + 2];
  atomicAdd(&cnt[(cellOf(z) * G + cellOf(y)) * G + cellOf(x)], 1u);
}

// Phase A: per-block partial sums. grid=(SB,2); y=0->counts1, y=1->counts0.
__global__ __launch_bounds__(1024) void scan_partial_kernel(
    const unsigned* __restrict__ counts0, const unsigned* __restrict__ counts1,
    unsigned* __restrict__ partials) {
  const unsigned* counts = blockIdx.y ? counts0 : counts1;
  const int base = blockIdx.x * CHUNK + threadIdx.x * 2;
  unsigned sum = counts[base] + counts[base + 1];
  for (int o = 32; o; o >>= 1) sum += __shfl_down(sum, o, 64);
  __shared__ unsigned ws[16];
  if ((threadIdx.x & 63) == 0) ws[threadIdx.x >> 6] = sum;
  __syncthreads();
  if (threadIdx.x == 0) {
    unsigned t = 0;
    for (int w = 0; w < 16; ++w) t += ws[w];
    partials[blockIdx.y * SB + blockIdx.x] = t;
  }
}

// Phase B: one 256-thread block exclusively scans both 128-entry partial arrays.
__global__ __launch_bounds__(256) void scan_mid_kernel(
    unsigned* __restrict__ partials) {
  const int tid = threadIdx.x;
  const int g   = tid >> 7;
  const int li  = tid & 127;
  const unsigned v = partials[g * SB + li];
  unsigned inc = v;
  for (int o = 1; o < 64; o <<= 1) {
    const unsigned t = __shfl_up(inc, o, 64);
    if ((tid & 63) >= o) inc += t;
  }
  __shared__ unsigned wt[4];
  if ((tid & 63) == 63) wt[tid >> 6] = inc;
  __syncthreads();
  const unsigned woff = ((tid >> 6) & 1) ? wt[g << 1] : 0u;
  partials[g * SB + li] = woff + inc - v;
}

// Phase C: block scan + offset -> cur (CSR starts). grid=(SB,2).
__global__ __launch_bounds__(1024) void scan_final_kernel(
    const unsigned* __restrict__ counts0, unsigned* __restrict__ cur0,
    const unsigned* __restrict__ counts1, unsigned* __restrict__ cur1,
    const unsigned* __restrict__ partials) {
  const unsigned* counts = blockIdx.y ? counts0 : counts1;
  unsigned* cur          = blockIdx.y ? cur0    : cur1;
  const int tid = threadIdx.x;
  const int base = blockIdx.x * CHUNK + tid * 2;
  const unsigned a = counts[base], b = counts[base + 1];
  const unsigned tsum = a + b;
  unsigned inc = tsum;
  for (int o = 1; o < 64; o <<= 1) {
    const unsigned t = __shfl_up(inc, o, 64);
    if ((tid & 63) >= o) inc += t;
  }
  __shared__ unsigned wt[16];
  if ((tid & 63) == 63) wt[tid >> 6] = inc;
  __syncthreads();
  if (tid < 16) {
    unsigned w = wt[tid];
    for (int o = 1; o < 16; o <<= 1) {
      const unsigned t = __shfl_up(w, o, 16);
      if (tid >= o) w += t;
    }
    wt[tid] = w;
  }
  __syncthreads();
  const unsigned woff = (tid >> 6) ? wt[(tid >> 6) - 1] : 0u;
  const unsigned off =
      partials[blockIdx.y * SB + blockIdx.x] + woff + inc - tsum;
  cur[base] = off;
  cur[base + 1] = off + a;
}

// After scatter, cur[c] = CSR inclusive end of cell c (start = cur[c-1]).
__global__ __launch_bounds__(BLOCK) void scatter_kernel(
    const float* __restrict__ pc0, const float* __restrict__ pc1,
    unsigned* __restrict__ cur0, unsigned* __restrict__ cur1,
    float4* __restrict__ q, float4* __restrict__ s) {
  const int gid = blockIdx.x * BLOCK + threadIdx.x;
  const float* p; unsigned* cur; float4* dst; int i;
  if (gid < NPTS) { p = pc1; cur = cur1; dst = s; i = gid; }
  else            { p = pc0; cur = cur0; dst = q; i = gid - NPTS; }
  const float x = p[3 * i], y = p[3 * i + 1], z = p[3 * i + 2];
  const int cid = (cellOf(z) * G + cellOf(y)) * G + cellOf(x);
  dst[atomicAdd(&cur[cid], 1u)] = make_float4(x, y, z, 0.f);
}

// Phase 1: fine rings 0..1, 4 lanes per query; push unfinished to worklist.
// Exactness bound = per-point distance to the unscanned exterior (dbox), not
// the worst-case H.
__global__ __launch_bounds__(BLOCK) void query_kernel(
    const float4* __restrict__ q, const unsigned* __restrict__ ends,
    const float4* __restrict__ s,
    unsigned* __restrict__ wl, float* __restrict__ wlBest,
    unsigned* __restrict__ pendCnt, float* __restrict__ bkt) {
  const int gtid = blockIdx.x * BLOCK + threadIdx.x;
  const int i   = gtid >> 2;        // query index
  const int sub = gtid & 3;         // sub-lane (4 per query)
  const float4 p = q[i];
  const int cx = cellOf(p.x), cy = cellOf(p.y), cz = cellOf(p.z);
  const int x0 = max(cx - 1, 0), x1 = min(cx + 1, G - 1);

  unsigned rs[9], re[9];
#pragma unroll
  for (int rr = 0; rr < 9; ++rr) {
    const int zz = cz + rr / 3 - 1, yy = cy + rr % 3 - 1;
    const bool ok = (zz >= 0) && (zz < G) && (yy >= 0) && (yy < G);
    const int rb = ok ? (zz * G + yy) * G : 0;
    rs[rr] = ok ? ((rb + x0) ? ends[rb + x0 - 1] : 0u) : 0u;
    re[rr] = ok ? ends[rb + x1] : 0u;
  }
  float best = 3.4e38f;
#pragma unroll
  for (int rr = 0; rr < 9; ++rr) {
#pragma unroll 4
    for (unsigned j = rs[rr] + sub; j < re[rr]; j += 4) {
      const float4 c = s[j];
      const float dx = p.x - c.x, dy = p.y - c.y, dz = p.z - c.z;
      best = fminf(best, fmaf(dx, dx, fmaf(dy, dy, dz * dz)));
    }
  }
  // combine the 4 sub-lanes (lanes i*4 .. i*4+3 are in the same wave)
  best = fminf(best, __shfl_xor(best, 1, 64));
  best = fminf(best, __shfl_xor(best, 2, 64));

  float v = 0.f, c = 0.f;
  if (sub == 0) {
    // dbox = min distance from p to the unscanned exterior of the scanned
    // 3x3x3 fine box. Clamped faces (x0==0 / x1==G-1 etc.) have NO points
    // beyond them (cellOf clamps into [0,G-1]) -> treat as +inf.
    const int y0 = max(cy - 1, 0), y1 = min(cy + 1, G - 1);
    const int z0 = max(cz - 1, 0), z1 = min(cz + 1, G - 1);
    const float dxl = (x0 == 0)     ? 1e9f : p.x - (ORG + (float)x0 * H);
    const float dxr = (x1 == G - 1) ? 1e9f : (ORG + (float)(x1 + 1) * H) - p.x;
    const float dyl = (y0 == 0)     ? 1e9f : p.y - (ORG + (float)y0 * H);
    const float dyr = (y1 == G - 1) ? 1e9f : (ORG + (float)(y1 + 1) * H) - p.y;
    const float dzl = (z0 == 0)     ? 1e9f : p.z - (ORG + (float)z0 * H);
    const float dzr = (z1 == G - 1) ? 1e9f : (ORG + (float)(z1 + 1) * H) - p.z;
    const float dbox = fminf(fminf(fminf(dxl, dxr), fminf(dyl, dyr)),
                             fminf(dzl, dzr));
    const float bnd2 = dbox * dbox * 0.999999f;   // conservative vs rounding
    if (best > bnd2) {             // not provably exact -> phase 2
      const unsigned k = atomicAdd(pendCnt, 1u);
      wl[k] = (unsigned)i; wlBest[k] = best;
    } else if (best <= 2.0f) { v = best; c = 1.0f; }
  }

  for (int o = 32; o; o >>= 1) {
    v += __shfl_down(v, o, 64);
    c += __shfl_down(c, o, 64);
  }
  __shared__ float wsum[BLOCK / 64], wcnt[BLOCK / 64];
  const int wid = threadIdx.x >> 6;
  if ((threadIdx.x & 63) == 0) { wsum[wid] = v; wcnt[wid] = c; }
  __syncthreads();
  if (threadIdx.x == 0) {
    float bv = 0.f, bc = 0.f;
    for (int w = 0; w < BLOCK / 64; ++w) { bv += wsum[w]; bc += wcnt[w]; }
    if (bc != 0.f) {
      atomicAdd(&bkt[2 * (blockIdx.x & 63) + 0], bv);
      atomicAdd(&bkt[2 * (blockIdx.x & 63) + 1], bc);
    }
  }
}

// Phase 2: one wave per pending query; MEDIUM ring geometry over the FINE CSR
// (one medium row = 4 fine rows). Ring 1 = full 3x3x3 medium; r=8 head always
// terminates. Branch-and-bound row prune (box y/z distance + x-span clip to
// the ball of radius sqrt(min(b,2)) around p) -- exact, verified R3.
__global__ __launch_bounds__(BLOCK) void pending_kernel(
    const float4* __restrict__ q,
    const unsigned* __restrict__ ends, const float4* __restrict__ s,
    const unsigned* __restrict__ wl, const float* __restrict__ wlBest,
    unsigned* __restrict__ pendCnt, float* __restrict__ bkt,
    unsigned* __restrict__ done, float* __restrict__ out) {
  __shared__ int snP;
  __shared__ float wsum[BLOCK / 64], wcnt[BLOCK / 64];
  __shared__ int isLast;
  __shared__ float fs[BLOCK / 64], fc[BLOCK / 64];
  if (threadIdx.x == 0) snP = (int)atomicAdd(pendCnt, 0u);
  __syncthreads();
  const int lane = threadIdx.x & 63, wid = threadIdx.x >> 6;
  const int gw = blockIdx.x * (BLOCK / 64) + wid;
  const int nW = PBLOCKS * (BLOCK / 64);
  float v = 0.f, c = 0.f;

  for (int it = gw; it < snP; it += nW) {
    const unsigned qi = wl[it];
    const float4 p = q[qi];
    const int cx = cellOf3(p.x), cy = cellOf3(p.y), cz = cellOf3(p.z);
    float best = wlBest[it];   // wave-uniform (same address)

    for (int r = 1; r <= 8; ++r) {
      const float cov = H3 * (float)(r - 1);    // unscanned dist lower bound
      if (best <= cov * cov) break;             // exact
      if (best > 2.0f && cov * cov >= 2.0f) break;  // masked out either way
      const int S = (r == 1) ? 9 : 8 * r + 2 * (2 * r - 1) * (2 * r - 1);
      float b = best;
      for (int sI = lane; sI < S; sI += 64) {
        int dz, dy, xa, xb;
        if (r == 1) {                           // full 3x3x3 medium rows
          dz = sI / 3 - 1; dy = sI % 3 - 1; xa = cx - 1; xb = cx + 1;
        } else if (sI < 8 * r) {                // shell faces: full x rows
          if (sI < 2 * r + 1)      { dz = -r; dy = sI - r; }
          else if (sI < 4 * r + 2) { dz =  r; dy = sI - (2 * r + 1) - r; }
          else { const int t2 = sI - (4 * r + 2); dz = (t2 >> 1) - (r - 1);
                 dy = (t2 & 1) ? r : -r; }
          xa = cx - r; xb = cx + r;
        } else {                                // interior rows: x = +/- r ends
          const int t2 = sI - 8 * r, ci = t2 >> 1, w1 = 2 * r - 1;
          dz = ci / w1 - (r - 1); dy = ci % w1 - (r - 1);
          xa = xb = (t2 & 1) ? cx + r : cx - r;
        }
        const int Z = cz + dz, Y = cy + dy;
        if (Z < 0 || Z >= G3 || Y < 0 || Y >= G3) continue;
        int a3 = max(xa, 0), e3 = min(xb, G3 - 1);
        if (a3 > e3) continue;
        // --- branch-and-bound row prune (exact) -------------------------
        const float ylo = ORG + (float)Y * H3;
        const float zlo = ORG + (float)Z * H3;
        const float dyd = fmaxf(fmaxf(ylo - p.y, p.y - (ylo + H3)), 0.f);
        const float dzd = fmaxf(fmaxf(zlo - p.z, p.z - (zlo + H3)), 0.f);
        const float dyz2 = dyd * dyd + dzd * dzd;
        const float bnd = fminf(b, 2.0f);
        if (dyz2 >= bnd) continue;
        const float halfx = sqrtf(bnd - dyz2);
        const int xlo = (int)floorf((p.x - halfx - ORG) * INVH3);
        const int xhi = (int)floorf((p.x + halfx - ORG) * INVH3);
        a3 = max(a3, xlo); e3 = min(e3, xhi);
        if (a3 > e3) continue;
        // ----------------------------------------------------------------
        const int xs = 2 * a3, xe = 2 * e3 + 1; // fine x-span
        // 4 fine rows per medium row; ranges preloaded (independent loads)
        unsigned js[4], je[4];
#pragma unroll
        for (int k = 0; k < 4; ++k) {
          const int zz = 2 * Z + (k >> 1), yy = 2 * Y + (k & 1);
          const int rb = (zz * G + yy) * G;
          js[k] = (rb + xs) ? ends[rb + xs - 1] : 0u;
          je[k] = ends[rb + xe];
        }
#pragma unroll
        for (int k = 0; k < 4; ++k) {
#pragma unroll 4
          for (unsigned j = js[k]; j < je[k]; ++j) {
            const float4 cd = s[j];
            const float dx = p.x - cd.x, dyv = p.y - cd.y, dzv = p.z - cd.z;
            b = fminf(b, fmaf(dx, dx, fmaf(dyv, dyv, dzv * dzv)));
          }
        }
      }
      for (int o = 32; o; o >>= 1) b = fminf(b, __shfl_xor(b, o, 64));
      best = b;                                 // wave-uniform again
    }
    if (lane == 0 && best <= 2.0f) { v += best; c += 1.0f; }
  }

  if (lane == 0) { wsum[wid] = v; wcnt[wid] = c; }
  __syncthreads();
  if (threadIdx.x == 0) {
    float bv = 0.f, bc = 0.f;
    for (int w = 0; w < BLOCK / 64; ++w) { bv += wsum[w]; bc += wcnt[w]; }
    if (bc != 0.f) {
      atomicAdd(&bkt[2 * (blockIdx.x & 63) + 0], bv);
      atomicAdd(&bkt[2 * (blockIdx.x & 63) + 1], bc);
    }
    __threadfence();
    isLast = (atomicAdd(done, 1u) == (unsigned)(PBLOCKS - 1));
  }
  __syncthreads();
  if (isLast) {   // parallel coherent read of the 128 bucket slots + reduce
    const float val = (threadIdx.x < 128) ? atomicAdd(&bkt[threadIdx.x], 0.0f) : 0.0f;
    float sv = (threadIdx.x & 1) ? 0.f : val;
    float cv = (threadIdx.x & 1) ? val : 0.f;
    for (int o = 32; o; o >>= 1) {
      sv += __shfl_down(sv, o, 64);
      cv += __shfl_down(cv, o, 64);
    }
    if (lane == 0) { fs[wid] = sv; fc[wid] = cv; }
    __syncthreads();
    if (threadIdx.x == 0) {
      float S = 0.f, C = 0.f;
      for (int w = 0; w < BLOCK / 64; ++w) { S += fs[w]; C += fc[w]; }
      out[0] = S / C;
    }
  }
}

extern "C" void kernel_launch(void* const* d_in, const int* in_sizes, int n_in,
                              void* d_out, int out_size, void* d_ws, size_t ws_size,
                              hipStream_t stream) {
  const float* pc0 = (const float*)d_in[0];
  const float* pc1 = (const float*)d_in[1];
  float* out = (float*)d_out;

  // slab carve-up; counts1|counts0|misc contiguous -> single memset
  char* w = (char*)d_ws;
  auto nxt = [&](size_t bytes) {
    char* p = w; w += (bytes + 255) & ~(size_t)255; return p;
  };
  unsigned* counts1  = (unsigned*)nxt((size_t)NC * 4);           // 1 MB
  unsigned* counts0  = (unsigned*)nxt((size_t)NC * 4);           // 1 MB
  char*     misc     = nxt(1024);   // bkt[128] | done | pendCnt
  float*    bkt      = (float*)misc;
  unsigned* done     = (unsigned*)(misc + 512);
  unsigned* pendCnt  = (unsigned*)(misc + 516);
  unsigned* partials = (unsigned*)nxt((size_t)2 * SB * 4);       // 1 KB
  unsigned* cur1     = (unsigned*)nxt((size_t)NC * 4);           // 1 MB
  unsigned* cur0     = (unsigned*)nxt((size_t)NC * 4);           // 1 MB
  float4*   s        = (float4*)nxt((size_t)NPTS * 16);          // 1 MB
  float4*   q        = (float4*)nxt((size_t)NPTS * 16);          // 1 MB
  unsigned* wl       = (unsigned*)nxt((size_t)NPTS * 4);         // 256 KB
  float*    wlBest   = (float*)nxt((size_t)NPTS * 4);            // 256 KB

  hipMemsetAsync(counts1, 0, (size_t)2 * NC * 4 + 1024, stream);

  count_kernel<<<2 * NPTS / BLOCK, BLOCK, 0, stream>>>(pc0, pc1, counts0, counts1);
  scan_partial_kernel<<<dim3(SB, 2), 1024, 0, stream>>>(counts0, counts1, partials);
  scan_mid_kernel<<<1, 256, 0, stream>>>(partials);
  scan_final_kernel<<<dim3(SB, 2), 1024, 0, stream>>>(counts0, cur0,
                                                      counts1, cur1, partials);
  scatter_kernel<<<2 * NPTS / BLOCK, BLOCK, 0, stream>>>(
      pc0, pc1, cur0, cur1, q, s);
  query_kernel<<<4 * NPTS / BLOCK, BLOCK, 0, stream>>>(q, cur1, s, wl, wlBest,
                                                       pendCnt, bkt);
  pending_kernel<<<PBLOCKS, BLOCK, 0, stream>>>(q, cur1, s, wl, wlBest,
                                                pendCnt, bkt, done, out);
}